// Round 4
// baseline (221.918 us; speedup 1.0000x reference)
//
#include <hip/hip_runtime.h>
#include <hip/hip_bf16.h>
#include <math.h>

#define NN 4096
#define IN_DIM 256
#define OUT_DIM 128
#define HEADS 4
#define SUB 32
#define MAXDEG 128
#define ETA 0.5f
#define INV_SQRT_SUB 0.17677669529663687f
#define SCAN_BLOCKS 2048
#define RPB 8

// ---- K0: Wcomb[c][d] prep | W2T[o][hs] | orth loss partials ----
__global__ __launch_bounds__(256) void k_prep(const float* __restrict__ U,
                                              const float* __restrict__ PW,
                                              float* __restrict__ Wcomb,
                                              float* __restrict__ W2T,
                                              float* __restrict__ loss_parts) {
    int b = blockIdx.x, t = threadIdx.x;
    __shared__ float sh[260];
    if (b < 256) {
        float v;
        if (b < 128) { int h = b >> 5, s = b & 31; v = U[h * IN_DIM * SUB + t * SUB + s]; }
        else          v = PW[(b - 128) * IN_DIM + t];
        Wcomb[b * IN_DIM + t] = v;
    } else if (b < 384) {
        int hs = b - 256, h = hs >> 5, s = hs & 31;
        sh[t] = U[h * IN_DIM * SUB + t * SUB + s];
        __syncthreads();
        if (t < 128) {
            const float4* pw4 = (const float4*)(PW + t * IN_DIM);
            const float4* u4  = (const float4*)sh;
            float acc = 0.f;
            #pragma unroll 8
            for (int d4 = 0; d4 < 64; ++d4) {
                float4 a = u4[d4], p = pw4[d4];
                acc += a.x * p.x + a.y * p.y + a.z * p.z + a.w * p.w;
            }
            W2T[t * OUT_DIM + hs] = acc;       // [o][hs]
        }
    } else {
        const int pk[10] = {0,0,0,0,1,1,1,2,2,3};
        const int pl[10] = {0,1,2,3,1,2,3,2,3,3};
        int p = b - 384, k = pk[p], l = pl[p];
        int t2 = t & 31, sg = t >> 5;
        const float* Uk = U + k * IN_DIM * SUB;
        const float* Ul = U + l * IN_DIM * SUB;
        float a0 = 0.f, a1 = 0.f, a2 = 0.f, a3 = 0.f;
        #pragma unroll 4
        for (int d = 0; d < IN_DIM; ++d) {
            float ul = Ul[d * SUB + t2];
            float u0 = Uk[d * SUB + sg * 4 + 0];
            float u1 = Uk[d * SUB + sg * 4 + 1];
            float u2 = Uk[d * SUB + sg * 4 + 2];
            float u3 = Uk[d * SUB + sg * 4 + 3];
            a0 += u0 * ul; a1 += u1 * ul; a2 += u2 * ul; a3 += u3 * ul;
        }
        if (k == l) {
            if (sg * 4 + 0 == t2) a0 -= 1.f;
            if (sg * 4 + 1 == t2) a1 -= 1.f;
            if (sg * 4 + 2 == t2) a2 -= 1.f;
            if (sg * 4 + 3 == t2) a3 -= 1.f;
        }
        float local = a0 * a0 + a1 * a1 + a2 * a2 + a3 * a3;
        local += __shfl_xor(local, 32, 64);
        local += __shfl_xor(local, 16, 64);
        local += __shfl_xor(local, 8, 64);
        local += __shfl_xor(local, 4, 64);
        local += __shfl_xor(local, 2, 64);
        local += __shfl_xor(local, 1, 64);
        if ((t & 63) == 0) sh[256 + (t >> 6)] = local;
        __syncthreads();
        if (t == 0) loss_parts[p] = sh[256] + sh[257] + sh[258] + sh[259];
    }
}

// ---- K_A: adjacency scan (blocks <2048, 2 rows each) + [ZT|P]=H@Wcomb^T ----
__global__ __launch_bounds__(256) void k_front(const float* __restrict__ H,
                                               const float* __restrict__ adj,
                                               const float* __restrict__ Wcomb,
                                               float* __restrict__ ZT,
                                               float* __restrict__ P,
                                               int* __restrict__ nbr,
                                               int* __restrict__ deg) {
    int b = blockIdx.x, t = threadIdx.x;
    __shared__ float Hs[RPB][IN_DIM];     // used by ztp branch
    __shared__ int cnt[2];                // used by scan branch
    if (b < SCAN_BLOCKS) {
        int half = t >> 7, u = t & 127;
        int row = b * 2 + half;
        if (u == 0) cnt[half] = 0;
        __syncthreads();
        const float4* row4 = (const float4*)(adj + (size_t)row * NN);
        int* nrow = nbr + row * MAXDEG;
        #pragma unroll
        for (int k = 0; k < NN / (128 * 4); ++k) {
            float4 v = row4[u + k * 128];
            int j0 = (u + k * 128) * 4;
            if (v.x > 0.5f) { int p = atomicAdd(&cnt[half], 1); if (p < MAXDEG) nrow[p] = j0; }
            if (v.y > 0.5f) { int p = atomicAdd(&cnt[half], 1); if (p < MAXDEG) nrow[p] = j0 + 1; }
            if (v.z > 0.5f) { int p = atomicAdd(&cnt[half], 1); if (p < MAXDEG) nrow[p] = j0 + 2; }
            if (v.w > 0.5f) { int p = atomicAdd(&cnt[half], 1); if (p < MAXDEG) nrow[p] = j0 + 3; }
        }
        __syncthreads();
        if (u == 0) deg[row] = cnt[half] < MAXDEG ? cnt[half] : MAXDEG;
    } else {
        int r0 = (b - SCAN_BLOCKS) * RPB;
        const float4* H4 = (const float4*)(H + (size_t)r0 * IN_DIM);
        float4* Hs4 = (float4*)&Hs[0][0];
        Hs4[t]       = H4[t];
        Hs4[t + 256] = H4[t + 256];
        __syncthreads();
        float acc[RPB];
        #pragma unroll
        for (int r = 0; r < RPB; ++r) acc[r] = 0.f;
        const float4* Wr = (const float4*)(Wcomb + t * IN_DIM);
        #pragma unroll 4
        for (int d4 = 0; d4 < 64; ++d4) {
            float4 w = Wr[d4];
            #pragma unroll
            for (int r = 0; r < RPB; ++r) {
                float4 h = *(const float4*)&Hs[r][d4 * 4];
                acc[r] += h.x * w.x + h.y * w.y + h.z * w.z + h.w * w.w;
            }
        }
        #pragma unroll
        for (int r = 0; r < RPB; ++r) {
            if (t < 128) ZT[(size_t)(r0 + r) * 128 + t] = acc[r];
            else         P [(size_t)(r0 + r) * 128 + (t - 128)] = acc[r];
        }
    }
}

// ---- K_B: shuffle-free sparse attention + fused epilogue (2 rows/block) ----
__global__ __launch_bounds__(256) void k_attn(const float* __restrict__ ZT,
                                              const float* __restrict__ Pm,
                                              const float* __restrict__ W2T,
                                              const int* __restrict__ nbr,
                                              const int* __restrict__ deg,
                                              const float* __restrict__ threshold,
                                              const float* __restrict__ loss_parts,
                                              float* __restrict__ out) {
    int b = blockIdx.x, t = threadIdx.x;
    int half = t >> 7, u = t & 127;
    int row = b * 2 + half;
    __shared__ float z_s[2][128];
    __shared__ float e_s[2][MAXDEG][HEADS];
    __shared__ int   nbr_s[2][MAXDEG];
    __shared__ float agg_s[2][128];

    if (b == 0 && t == 0) {
        float L = 0.f;
        #pragma unroll
        for (int p = 0; p < 10; ++p) L += loss_parts[p];
        out[(size_t)NN * OUT_DIM] = L;
    }

    int dgv = deg[row];
    z_s[half][u] = ZT[(size_t)row * 128 + u];
    nbr_s[half][u] = (u < dgv) ? nbr[row * MAXDEG + u] : 0;
    __syncthreads();

    // phase B: lane = (neighbor jj0 = u>>2, head h = u&3); full 32-dot, no shuffles
    int jj0 = u >> 2, h = u & 3;
    int ntiles = (dgv + 31) >> 5;
    const float4* qr = (const float4*)(&z_s[half][h * 32]);
    for (int tile = 0; tile < ntiles; ++tile) {
        int jj = tile * 32 + jj0;
        int j = nbr_s[half][jj];
        const float4* zr = (const float4*)(ZT + (size_t)j * 128 + h * 32);
        float acc = 0.f;
        #pragma unroll
        for (int k = 0; k < 8; ++k) {
            float4 z = zr[k];
            float4 q = qr[k];
            acc += z.x * q.x + z.y * q.y + z.z * q.z + z.w * q.w;
        }
        e_s[half][jj][h] = (jj < dgv) ? __expf(acc * INV_SQRT_SUB) : 0.f;
    }
    __syncthreads();

    // phase C: agg over neighbors; whole wave reads one contiguous ZT row slice
    int hh = u >> 5;
    float accV = 0.f, accS = 0.f;
    const float* zbase = ZT + u;
    for (int jj = 0; jj < dgv; jj += 4) {
        int ja = nbr_s[half][jj],     jb = nbr_s[half][jj + 1];
        int jc = nbr_s[half][jj + 2], jd = nbr_s[half][jj + 3];
        float ea = e_s[half][jj][hh],     eb = e_s[half][jj + 1][hh];
        float ec = e_s[half][jj + 2][hh], ed = e_s[half][jj + 3][hh];
        float va = zbase[(size_t)ja * 128], vb = zbase[(size_t)jb * 128];
        float vc = zbase[(size_t)jc * 128], vd = zbase[(size_t)jd * 128];
        accV += ea * va + eb * vb + ec * vc + ed * vd;
        accS += (ea + eb) + (ec + ed);
    }
    agg_s[half][u] = accV * (ETA / accS);
    __syncthreads();

    // epilogue: out[row][u] = soft_thresh(P[row][u] + sum_hs agg[hs]*W2T[u][hs])
    float val = Pm[(size_t)row * 128 + u];
    const float4* w4 = (const float4*)(W2T + u * 128);
    const float4* a4 = (const float4*)(&agg_s[half][0]);
    #pragma unroll 8
    for (int k = 0; k < 32; ++k) {
        float4 w = w4[k], a = a4[k];
        val += w.x * a.x + w.y * a.y + w.z * a.z + w.w * a.w;
    }
    float th = threshold[u];
    float av = fabsf(val) - th;
    out[(size_t)row * 128 + u] = (av > 0.f) ? copysignf(av, val) : 0.f;
}

extern "C" void kernel_launch(void* const* d_in, const int* in_sizes, int n_in,
                              void* d_out, int out_size, void* d_ws, size_t ws_size,
                              hipStream_t stream) {
    const float* H   = (const float*)d_in[0];
    const float* adj = (const float*)d_in[1];
    const float* U   = (const float*)d_in[2];
    const float* thr = (const float*)d_in[3];
    const float* PW  = (const float*)d_in[4];
    float* out = (float*)d_out;

    char* ws = (char*)d_ws;
    float* ZT    = (float*)(ws);                          // 2 MB
    float* P     = (float*)(ws + (size_t)2097152);        // 2 MB
    float* Wcomb = (float*)(ws + (size_t)4194304);        // 256 KB
    float* W2T   = (float*)(ws + (size_t)4456448);        // 64 KB
    int*   nbr   = (int*)  (ws + (size_t)4521984);        // 2 MB
    int*   deg   = (int*)  (ws + (size_t)6619136);        // 16 KB
    float* lossp = (float*)(ws + (size_t)6635520);        // 40 B

    k_prep<<<394, 256, 0, stream>>>(U, PW, Wcomb, W2T, lossp);
    k_front<<<SCAN_BLOCKS + NN / RPB, 256, 0, stream>>>(H, adj, Wcomb, ZT, P, nbr, deg);
    k_attn<<<NN / 2, 256, 0, stream>>>(ZT, P, W2T, nbr, deg, thr, lossp, out);
}

// Round 5
// 176.239 us; speedup vs baseline: 1.2592x; 1.2592x over previous
//
#include <hip/hip_runtime.h>
#include <hip/hip_bf16.h>
#include <math.h>

#define NN 4096
#define IN_DIM 256
#define OUT_DIM 128
#define HEADS 4
#define SUB 32
#define MAXDEG 128
#define ETA 0.5f
#define INV_SQRT_SUB 0.17677669529663687f

// ---- K0 (fused small): prep Wcomb[c][d] | W2[hs][o] | orth loss ----
__global__ __launch_bounds__(256) void fused_small(const float* __restrict__ U,
                                                   const float* __restrict__ PW,
                                                   float* __restrict__ Wcomb,
                                                   float* __restrict__ W2,
                                                   float* __restrict__ loss) {
    int b = blockIdx.x;
    int t = threadIdx.x;
    __shared__ float sh[260];

    if (b < 256) {
        float v;
        if (b < 128) {
            int h = b >> 5, s = b & 31;
            v = U[h * IN_DIM * SUB + t * SUB + s];
        } else {
            v = PW[(b - 128) * IN_DIM + t];
        }
        Wcomb[b * IN_DIM + t] = v;
    } else if (b < 384) {
        int hs = b - 256;
        int h = hs >> 5, s = hs & 31;
        sh[t] = U[h * IN_DIM * SUB + t * SUB + s];
        __syncthreads();
        if (t < 128) {
            const float4* pw4 = (const float4*)(PW + t * IN_DIM);
            const float4* u4  = (const float4*)sh;
            float acc = 0.f;
            #pragma unroll 4
            for (int d4 = 0; d4 < 64; ++d4) {
                float4 a = u4[d4], p = pw4[d4];
                acc += a.x * p.x + a.y * p.y + a.z * p.z + a.w * p.w;
            }
            W2[hs * OUT_DIM + t] = acc;
        }
    } else {
        const int pk[10] = {0,0,0,0,1,1,1,2,2,3};
        const int pl[10] = {0,1,2,3,1,2,3,2,3,3};
        int p = b - 384;
        int k = pk[p], l = pl[p];
        int t2 = t & 31;
        int sg = t >> 5;
        const float* Uk = U + k * IN_DIM * SUB;
        const float* Ul = U + l * IN_DIM * SUB;
        float a0 = 0.f, a1 = 0.f, a2 = 0.f, a3 = 0.f;
        #pragma unroll 4
        for (int d = 0; d < IN_DIM; ++d) {
            float ul = Ul[d * SUB + t2];
            float u0 = Uk[d * SUB + sg * 4 + 0];
            float u1 = Uk[d * SUB + sg * 4 + 1];
            float u2 = Uk[d * SUB + sg * 4 + 2];
            float u3 = Uk[d * SUB + sg * 4 + 3];
            a0 += u0 * ul; a1 += u1 * ul; a2 += u2 * ul; a3 += u3 * ul;
        }
        if (k == l) {
            if (sg * 4 + 0 == t2) a0 -= 1.f;
            if (sg * 4 + 1 == t2) a1 -= 1.f;
            if (sg * 4 + 2 == t2) a2 -= 1.f;
            if (sg * 4 + 3 == t2) a3 -= 1.f;
        }
        float local = a0 * a0 + a1 * a1 + a2 * a2 + a3 * a3;
        local += __shfl_xor(local, 32, 64);
        local += __shfl_xor(local, 16, 64);
        local += __shfl_xor(local, 8, 64);
        local += __shfl_xor(local, 4, 64);
        local += __shfl_xor(local, 2, 64);
        local += __shfl_xor(local, 1, 64);
        if ((t & 63) == 0) sh[256 + (t >> 6)] = local;
        __syncthreads();
        if (t == 0) atomicAdd(loss, sh[256] + sh[257] + sh[258] + sh[259]);
    }
}

// ---- K1: [ZT | P] = H @ Wcomb^T, RPB=4, depth-2 w pipeline ----
#define RPB 4
__global__ __launch_bounds__(256) void compute_zt_p(const float* __restrict__ H,
                                                    const float* __restrict__ Wcomb,
                                                    float* __restrict__ ZT,
                                                    float* __restrict__ P) {
    int t = threadIdx.x;
    int r0 = blockIdx.x * RPB;
    __shared__ float Hs[RPB][IN_DIM];     // 4 KB
    const float4* H4 = (const float4*)(H + (size_t)r0 * IN_DIM);
    ((float4*)&Hs[0][0])[t] = H4[t];
    __syncthreads();

    float acc[RPB];
    #pragma unroll
    for (int r = 0; r < RPB; ++r) acc[r] = 0.f;

    const float4* Wr = (const float4*)(Wcomb + t * IN_DIM);
    float4 w0 = Wr[0], w1 = Wr[1];
    #pragma unroll 4
    for (int d4 = 0; d4 < 64; ++d4) {
        float4 wn = Wr[(d4 + 2 < 64) ? d4 + 2 : 63];
        float4 w = w0; w0 = w1; w1 = wn;
        #pragma unroll
        for (int r = 0; r < RPB; ++r) {
            float4 h = *(const float4*)&Hs[r][d4 * 4];
            acc[r] += h.x * w.x + h.y * w.y + h.z * w.z + h.w * w.w;
        }
    }
    #pragma unroll
    for (int r = 0; r < RPB; ++r) {
        if (t < 128) ZT[(size_t)(r0 + r) * 128 + t] = acc[r];
        else         P [(size_t)(r0 + r) * 128 + (t - 128)] = acc[r];
    }
}

// ---- K2: adj-scan (prefetched) + shuffle-free attention -> agg ----
__global__ __launch_bounds__(128) void attn_core(const float* __restrict__ ZT,
                                                 const float* __restrict__ adj,
                                                 float* __restrict__ agg) {
    int i = blockIdx.x;
    int t = threadIdx.x;
    __shared__ int   nbr_s[MAXDEG];
    __shared__ float e_s[MAXDEG][HEADS];
    __shared__ float z_s[128];
    __shared__ int cnt;

    // issue all 8 adjacency loads before anything else (32 VGPRs in flight)
    const float4* row4 = (const float4*)(adj + (size_t)i * NN);
    float4 v[8];
    #pragma unroll
    for (int k = 0; k < 8; ++k) v[k] = row4[t + k * 128];

    if (t == 0) cnt = 0;
    nbr_s[t] = 0;
    z_s[t] = ZT[(size_t)i * 128 + t];
    __syncthreads();

    #pragma unroll
    for (int k = 0; k < 8; ++k) {
        int j0 = (t + k * 128) * 4;
        if (v[k].x > 0.5f) { int p = atomicAdd(&cnt, 1); if (p < MAXDEG) nbr_s[p] = j0; }
        if (v[k].y > 0.5f) { int p = atomicAdd(&cnt, 1); if (p < MAXDEG) nbr_s[p] = j0 + 1; }
        if (v[k].z > 0.5f) { int p = atomicAdd(&cnt, 1); if (p < MAXDEG) nbr_s[p] = j0 + 2; }
        if (v[k].w > 0.5f) { int p = atomicAdd(&cnt, 1); if (p < MAXDEG) nbr_s[p] = j0 + 3; }
    }
    __syncthreads();
    int dg = cnt < MAXDEG ? cnt : MAXDEG;

    // phase B: lane = (neighbor jj0=t>>2, head h=t&3); full 32-dot, no shuffles
    int jj0 = t >> 2, h = t & 3;
    int ntiles = (dg + 31) >> 5;
    const float4* qr = (const float4*)(&z_s[h * 32]);
    for (int tile = 0; tile < ntiles; ++tile) {
        int jj = tile * 32 + jj0;
        int j = nbr_s[jj];                       // pre-inited to 0 beyond cnt
        const float4* zr = (const float4*)(ZT + (size_t)j * 128 + h * 32);
        float acc = 0.f;
        #pragma unroll
        for (int k = 0; k < 8; ++k) {
            float4 z = zr[k];
            float4 q = qr[k];
            acc += z.x * q.x + z.y * q.y + z.z * q.z + z.w * q.w;
        }
        e_s[jj][h] = (jj < dg) ? __expf(acc * INV_SQRT_SUB) : 0.f;
    }
    __syncthreads();

    // phase C: agg over neighbors; wave reads contiguous ZT row slices
    int hh = t >> 5;
    float accV = 0.f, accS = 0.f;
    const float* zbase = ZT + t;
    for (int jj = 0; jj < dg; jj += 4) {
        int ja = nbr_s[jj],     jb = nbr_s[jj + 1];
        int jc = nbr_s[jj + 2], jd = nbr_s[jj + 3];
        float ea = e_s[jj][hh],     eb = e_s[jj + 1][hh];
        float ec = e_s[jj + 2][hh], ed = e_s[jj + 3][hh];
        float va = zbase[(size_t)ja * 128], vb = zbase[(size_t)jb * 128];
        float vc = zbase[(size_t)jc * 128], vd = zbase[(size_t)jd * 128];
        accV += ea * va + eb * vb + ec * vc + ed * vd;
        accS += (ea + eb) + (ec + ed);
    }
    agg[(size_t)i * 128 + t] = accV * (ETA / accS);
}

// ---- K3: epilogue out = soft_thresh(P + agg @ W2), 16-row W2 reuse ----
#define EROWS 16
__global__ __launch_bounds__(256) void epilogue(const float* __restrict__ Pm,
                                                const float* __restrict__ agg,
                                                const float* __restrict__ W2,
                                                const float* __restrict__ threshold,
                                                float* __restrict__ out) {
    int t = threadIdx.x;
    int o = t & 127, half = t >> 7;
    int r0 = blockIdx.x * EROWS;
    __shared__ float As[EROWS][128];     // 8 KB
    const float4* a4 = (const float4*)(agg + (size_t)r0 * 128);
    float4* As4 = (float4*)&As[0][0];
    As4[t]       = a4[t];
    As4[t + 256] = a4[t + 256];
    __syncthreads();

    float acc[8];
    #pragma unroll
    for (int r = 0; r < 8; ++r) acc[r] = 0.f;

    for (int q4 = 0; q4 < 32; ++q4) {
        int hs = q4 * 4;
        float w0 = W2[(hs + 0) * 128 + o];
        float w1 = W2[(hs + 1) * 128 + o];
        float w2v = W2[(hs + 2) * 128 + o];
        float w3 = W2[(hs + 3) * 128 + o];
        #pragma unroll
        for (int r = 0; r < 8; ++r) {
            float4 a = *(const float4*)&As[half * 8 + r][hs];
            acc[r] += a.x * w0 + a.y * w1 + a.z * w2v + a.w * w3;
        }
    }
    float th = threshold[o];
    #pragma unroll
    for (int r = 0; r < 8; ++r) {
        int row = r0 + half * 8 + r;
        float val = Pm[(size_t)row * 128 + o] + acc[r];
        float av = fabsf(val) - th;
        out[(size_t)row * 128 + o] = (av > 0.f) ? copysignf(av, val) : 0.f;
    }
}

extern "C" void kernel_launch(void* const* d_in, const int* in_sizes, int n_in,
                              void* d_out, int out_size, void* d_ws, size_t ws_size,
                              hipStream_t stream) {
    const float* H   = (const float*)d_in[0];
    const float* adj = (const float*)d_in[1];
    const float* U   = (const float*)d_in[2];
    const float* thr = (const float*)d_in[3];
    const float* PW  = (const float*)d_in[4];
    float* out = (float*)d_out;
    float* loss = out + (size_t)NN * OUT_DIM;

    char* ws = (char*)d_ws;
    float* ZT    = (float*)(ws);                       // 2 MB
    float* P     = (float*)(ws + (size_t)2097152);     // 2 MB
    float* agg   = (float*)(ws + (size_t)4194304);     // 2 MB
    float* W2    = (float*)(ws + (size_t)6291456);     // 64 KB
    float* Wcomb = (float*)(ws + (size_t)6356992);     // 256 KB

    hipMemsetAsync(loss, 0, sizeof(float), stream);
    fused_small<<<394, 256, 0, stream>>>(U, PW, Wcomb, W2, loss);
    compute_zt_p<<<NN / RPB, 256, 0, stream>>>(H, Wcomb, ZT, P);
    attn_core<<<NN, 128, 0, stream>>>(ZT, adj, agg);
    epilogue<<<NN / EROWS, 256, 0, stream>>>(P, agg, W2, thr, out);
}

// Round 6
// 151.728 us; speedup vs baseline: 1.4626x; 1.1615x over previous
//
#include <hip/hip_runtime.h>
#include <hip/hip_bf16.h>
#include <math.h>

#define NN 4096
#define IN_DIM 256
#define OUT_DIM 128
#define HEADS 4
#define SUB 32
#define MAXDEG 128
#define ETA 0.5f
#define INV_SQRT_SUB 0.17677669529663687f

typedef __attribute__((ext_vector_type(8))) short bf16x8;
typedef __attribute__((ext_vector_type(4))) short s16x4;
typedef __attribute__((ext_vector_type(4))) float f32x4;

static __device__ inline short f2bf(float f) {
    unsigned u = __float_as_uint(f);
    unsigned r = u + 0x7FFFu + ((u >> 16) & 1u);
    return (short)(r >> 16);
}
static __device__ inline float bf2f(short s) {
    return __uint_as_float(((unsigned)(unsigned short)s) << 16);
}
#define MFMA16(a, b, c) __builtin_amdgcn_mfma_f32_16x16x32_bf16(a, b, c, 0, 0, 0)

// ---- K0: prep Wh/Wl (split-bf16 of [U cols | PW rows]) | W2 | orth loss partials ----
__global__ __launch_bounds__(256) void fused_small(const float* __restrict__ U,
                                                   const float* __restrict__ PW,
                                                   short* __restrict__ Wh,
                                                   short* __restrict__ Wl,
                                                   float* __restrict__ W2,
                                                   float* __restrict__ loss_parts) {
    int b = blockIdx.x;
    int t = threadIdx.x;
    __shared__ float sh[260];

    if (b < 256) {
        // row c=b of the combined weight (c<128: U column (h,s); else PW row), d=t
        float v;
        if (b < 128) {
            int h = b >> 5, s = b & 31;
            v = U[h * IN_DIM * SUB + t * SUB + s];
        } else {
            v = PW[(b - 128) * IN_DIM + t];
        }
        short hi = f2bf(v);
        Wh[b * IN_DIM + t] = hi;
        Wl[b * IN_DIM + t] = f2bf(v - bf2f(hi));
    } else if (b < 384) {
        int hs = b - 256;
        int h = hs >> 5, s = hs & 31;
        sh[t] = U[h * IN_DIM * SUB + t * SUB + s];
        __syncthreads();
        if (t < 128) {
            const float4* pw4 = (const float4*)(PW + t * IN_DIM);
            const float4* u4  = (const float4*)sh;
            float acc = 0.f;
            #pragma unroll 4
            for (int d4 = 0; d4 < 64; ++d4) {
                float4 a = u4[d4], p = pw4[d4];
                acc += a.x * p.x + a.y * p.y + a.z * p.z + a.w * p.w;
            }
            W2[hs * OUT_DIM + t] = acc;
        }
    } else {
        const int pk[10] = {0,0,0,0,1,1,1,2,2,3};
        const int pl[10] = {0,1,2,3,1,2,3,2,3,3};
        int p = b - 384;
        int k = pk[p], l = pl[p];
        int t2 = t & 31;
        int sg = t >> 5;
        const float* Uk = U + k * IN_DIM * SUB;
        const float* Ul = U + l * IN_DIM * SUB;
        float a0 = 0.f, a1 = 0.f, a2 = 0.f, a3 = 0.f;
        #pragma unroll 4
        for (int d = 0; d < IN_DIM; ++d) {
            float ul = Ul[d * SUB + t2];
            float u0 = Uk[d * SUB + sg * 4 + 0];
            float u1 = Uk[d * SUB + sg * 4 + 1];
            float u2 = Uk[d * SUB + sg * 4 + 2];
            float u3 = Uk[d * SUB + sg * 4 + 3];
            a0 += u0 * ul; a1 += u1 * ul; a2 += u2 * ul; a3 += u3 * ul;
        }
        if (k == l) {
            if (sg * 4 + 0 == t2) a0 -= 1.f;
            if (sg * 4 + 1 == t2) a1 -= 1.f;
            if (sg * 4 + 2 == t2) a2 -= 1.f;
            if (sg * 4 + 3 == t2) a3 -= 1.f;
        }
        float local = a0 * a0 + a1 * a1 + a2 * a2 + a3 * a3;
        local += __shfl_xor(local, 32, 64);
        local += __shfl_xor(local, 16, 64);
        local += __shfl_xor(local, 8, 64);
        local += __shfl_xor(local, 4, 64);
        local += __shfl_xor(local, 2, 64);
        local += __shfl_xor(local, 1, 64);
        if ((t & 63) == 0) sh[256 + (t >> 6)] = local;
        __syncthreads();
        if (t == 0) loss_parts[p] = sh[256] + sh[257] + sh[258] + sh[259];
    }
}

// ---- K1: [ZT | P] = H @ W^T via split-bf16 MFMA (3-term, fp32-accurate) ----
#define LDA 264   // 256 + 8 shorts pad -> 2-way-only LDS bank aliasing
__global__ __launch_bounds__(256) void ztp_mfma(const float* __restrict__ H,
                                                const short* __restrict__ Wh,
                                                const short* __restrict__ Wl,
                                                float* __restrict__ ZT,
                                                float* __restrict__ P) {
    __shared__ short Ah[16 * LDA];
    __shared__ short Al[16 * LDA];
    int t = threadIdx.x, b = blockIdx.x;
    int m0 = (b >> 1) * 16, chalf = b & 1;

    // stage 16 rows x 256 d of H as bf16 hi/lo into LDS (each thread: 16 elems)
    {
        int r = t >> 4, dbase = (t & 15) * 16;
        const float4* src = (const float4*)(H + (size_t)(m0 + r) * IN_DIM + dbase);
        #pragma unroll
        for (int q = 0; q < 4; ++q) {
            float4 f = src[q];
            float fv[4] = {f.x, f.y, f.z, f.w};
            s16x4 hi, lo;
            #pragma unroll
            for (int j = 0; j < 4; ++j) {
                short h = f2bf(fv[j]);
                hi[j] = h;
                lo[j] = f2bf(fv[j] - bf2f(h));
            }
            *(s16x4*)&Ah[r * LDA + dbase + q * 4] = hi;
            *(s16x4*)&Al[r * LDA + dbase + q * 4] = lo;
        }
    }
    __syncthreads();

    int wave = t >> 6, lane = t & 63;
    int c0 = chalf * 128 + wave * 32;          // wave's 32 output columns
    int arow = lane & 15, agrp = lane >> 4;    // A row / k-group

    const short* ahp = &Ah[arow * LDA + agrp * 8];
    const short* alp = &Al[arow * LDA + agrp * 8];
    const short* bh0 = Wh + (size_t)(c0 + arow) * IN_DIM + agrp * 8;
    const short* bl0 = Wl + (size_t)(c0 + arow) * IN_DIM + agrp * 8;
    const short* bh1 = bh0 + 16 * IN_DIM;
    const short* bl1 = bl0 + 16 * IN_DIM;

    f32x4 acc0 = {0.f, 0.f, 0.f, 0.f};
    f32x4 acc1 = {0.f, 0.f, 0.f, 0.f};

    #pragma unroll
    for (int kk = 0; kk < 8; ++kk) {
        int d0 = kk * 32;
        bf16x8 a_h = *(const bf16x8*)(ahp + d0);
        bf16x8 a_l = *(const bf16x8*)(alp + d0);
        bf16x8 b0h = *(const bf16x8*)(bh0 + d0);
        bf16x8 b0l = *(const bf16x8*)(bl0 + d0);
        bf16x8 b1h = *(const bf16x8*)(bh1 + d0);
        bf16x8 b1l = *(const bf16x8*)(bl1 + d0);
        acc0 = MFMA16(a_h, b0h, acc0);
        acc0 = MFMA16(a_h, b0l, acc0);
        acc0 = MFMA16(a_l, b0h, acc0);
        acc1 = MFMA16(a_h, b1h, acc1);
        acc1 = MFMA16(a_h, b1l, acc1);
        acc1 = MFMA16(a_l, b1h, acc1);
    }

    // C/D layout: col = lane&15, row = (lane>>4)*4 + reg
    float* dst = chalf ? P : ZT;
    int colbase = c0 - chalf * 128;
    #pragma unroll
    for (int i = 0; i < 4; ++i) {
        int row = m0 + agrp * 4 + i;
        dst[(size_t)row * 128 + colbase + arow]      = acc0[i];
        dst[(size_t)row * 128 + colbase + 16 + arow] = acc1[i];
    }
}

// ---- K2: adj-scan (prefetched) + shuffle-free attention -> agg ----
__global__ __launch_bounds__(128) void attn_core(const float* __restrict__ ZT,
                                                 const float* __restrict__ adj,
                                                 float* __restrict__ agg) {
    int i = blockIdx.x;
    int t = threadIdx.x;
    __shared__ int   nbr_s[MAXDEG];
    __shared__ float e_s[MAXDEG][HEADS];
    __shared__ float z_s[128];
    __shared__ int cnt;

    const float4* row4 = (const float4*)(adj + (size_t)i * NN);
    float4 v[8];
    #pragma unroll
    for (int k = 0; k < 8; ++k) v[k] = row4[t + k * 128];

    if (t == 0) cnt = 0;
    nbr_s[t] = 0;
    z_s[t] = ZT[(size_t)i * 128 + t];
    __syncthreads();

    #pragma unroll
    for (int k = 0; k < 8; ++k) {
        int j0 = (t + k * 128) * 4;
        if (v[k].x > 0.5f) { int p = atomicAdd(&cnt, 1); if (p < MAXDEG) nbr_s[p] = j0; }
        if (v[k].y > 0.5f) { int p = atomicAdd(&cnt, 1); if (p < MAXDEG) nbr_s[p] = j0 + 1; }
        if (v[k].z > 0.5f) { int p = atomicAdd(&cnt, 1); if (p < MAXDEG) nbr_s[p] = j0 + 2; }
        if (v[k].w > 0.5f) { int p = atomicAdd(&cnt, 1); if (p < MAXDEG) nbr_s[p] = j0 + 3; }
    }
    __syncthreads();
    int dg = cnt < MAXDEG ? cnt : MAXDEG;

    // phase B: lane=(neighbor, head): full 32-dot, no shuffles
    int jj0 = t >> 2, h = t & 3;
    int ntiles = (dg + 31) >> 5;
    const float4* qr = (const float4*)(&z_s[h * 32]);
    for (int tile = 0; tile < ntiles; ++tile) {
        int jj = tile * 32 + jj0;
        int j = nbr_s[jj];
        const float4* zr = (const float4*)(ZT + (size_t)j * 128 + h * 32);
        float acc = 0.f;
        #pragma unroll
        for (int k = 0; k < 8; ++k) {
            float4 z = zr[k];
            float4 q = qr[k];
            acc += z.x * q.x + z.y * q.y + z.z * q.z + z.w * q.w;
        }
        e_s[jj][h] = (jj < dg) ? __expf(acc * INV_SQRT_SUB) : 0.f;
    }
    __syncthreads();

    // phase C: weighted aggregation, coalesced ZT row slices
    int hh = t >> 5;
    float accV = 0.f, accS = 0.f;
    const float* zbase = ZT + t;
    for (int jj = 0; jj < dg; jj += 4) {
        int ja = nbr_s[jj],     jb = nbr_s[jj + 1];
        int jc = nbr_s[jj + 2], jd = nbr_s[jj + 3];
        float ea = e_s[jj][hh],     eb = e_s[jj + 1][hh];
        float ec = e_s[jj + 2][hh], ed = e_s[jj + 3][hh];
        float va = zbase[(size_t)ja * 128], vb = zbase[(size_t)jb * 128];
        float vc = zbase[(size_t)jc * 128], vd = zbase[(size_t)jd * 128];
        accV += ea * va + eb * vb + ec * vc + ed * vd;
        accS += (ea + eb) + (ec + ed);
    }
    agg[(size_t)i * 128 + t] = accV * (ETA / accS);
}

// ---- K3: epilogue out = soft_thresh(P + agg @ W2) + loss finalize ----
#define EROWS 16
__global__ __launch_bounds__(256) void epilogue(const float* __restrict__ Pm,
                                                const float* __restrict__ agg,
                                                const float* __restrict__ W2,
                                                const float* __restrict__ threshold,
                                                const float* __restrict__ loss_parts,
                                                float* __restrict__ out) {
    int t = threadIdx.x;
    int o = t & 127, half = t >> 7;
    int r0 = blockIdx.x * EROWS;
    __shared__ float As[EROWS][128];
    const float4* a4 = (const float4*)(agg + (size_t)r0 * 128);
    float4* As4 = (float4*)&As[0][0];
    As4[t]       = a4[t];
    As4[t + 256] = a4[t + 256];

    if (blockIdx.x == 0 && t == 0) {
        float L = 0.f;
        #pragma unroll
        for (int p = 0; p < 10; ++p) L += loss_parts[p];
        out[(size_t)NN * OUT_DIM] = L;
    }
    __syncthreads();

    float acc[8];
    #pragma unroll
    for (int r = 0; r < 8; ++r) acc[r] = 0.f;

    for (int q4 = 0; q4 < 32; ++q4) {
        int hs = q4 * 4;
        float w0 = W2[(hs + 0) * 128 + o];
        float w1 = W2[(hs + 1) * 128 + o];
        float w2v = W2[(hs + 2) * 128 + o];
        float w3 = W2[(hs + 3) * 128 + o];
        #pragma unroll
        for (int r = 0; r < 8; ++r) {
            float4 a = *(const float4*)&As[half * 8 + r][hs];
            acc[r] += a.x * w0 + a.y * w1 + a.z * w2v + a.w * w3;
        }
    }
    float th = threshold[o];
    #pragma unroll
    for (int r = 0; r < 8; ++r) {
        int row = r0 + half * 8 + r;
        float val = Pm[(size_t)row * 128 + o] + acc[r];
        float av = fabsf(val) - th;
        out[(size_t)row * 128 + o] = (av > 0.f) ? copysignf(av, val) : 0.f;
    }
}

extern "C" void kernel_launch(void* const* d_in, const int* in_sizes, int n_in,
                              void* d_out, int out_size, void* d_ws, size_t ws_size,
                              hipStream_t stream) {
    const float* H   = (const float*)d_in[0];
    const float* adj = (const float*)d_in[1];
    const float* U   = (const float*)d_in[2];
    const float* thr = (const float*)d_in[3];
    const float* PW  = (const float*)d_in[4];
    float* out = (float*)d_out;

    char* ws = (char*)d_ws;
    float* ZT    = (float*)(ws);                       // 2 MB
    float* P     = (float*)(ws + (size_t)2097152);     // 2 MB
    float* agg   = (float*)(ws + (size_t)4194304);     // 2 MB
    float* W2    = (float*)(ws + (size_t)6291456);     // 64 KB
    short* Wh    = (short*)(ws + (size_t)6356992);     // 128 KB
    short* Wl    = (short*)(ws + (size_t)6488064);     // 128 KB
    float* lossp = (float*)(ws + (size_t)6619136);     // 40 B

    fused_small<<<394, 256, 0, stream>>>(U, PW, Wh, Wl, W2, lossp);
    ztp_mfma<<<NN / 16 * 2, 256, 0, stream>>>(H, Wh, Wl, ZT, P);
    attn_core<<<NN, 128, 0, stream>>>(ZT, adj, agg);
    epilogue<<<NN / EROWS, 256, 0, stream>>>(P, agg, W2, thr, lossp, out);
}